// Round 6
// baseline (112.903 us; speedup 1.0000x reference)
//
#include <hip/hip_runtime.h>
#include <math.h>

// SSM diagonal scan, fused chunked-scan v4: barrier-free flag-pipelined combine.
//   reference: h_t = dA ⊙ h_{t-1} + dB·x_t ;  y_t = <C, h_t>
//   dt=exp(log_dt), A=exp(A_log), dA=exp(dt*A), dB=dt*B  (time-invariant).
// Algebra: u_n(t) = dA_n·u_n(t-1) + x_t, y_t = Σ_n dBC_n·u_n, dBC = dt·B·C.
// Carries combine in u-space with dA^CL = exp(CL·dt·A).
//
// Round-5 postmortem: v3 (2 block-wide __syncthreads) ~27us vs 10.6us traffic
// floor; v1==v3 despite layout fix -> stall is PHASE SERIALIZATION: all 16 waves
// finish reads before any wave writes; reads and writes never overlap.
// v4: drop both barriers. Wave 15 = publisher: polls per-chunk U-ready flags,
// chains H, publishes carry_c incrementally (carry_c available right after
// U_{c-1}..U_0, i.e. while waves c+1..15 still read x). Wave 0 never waits
// (carry=0); wave 15's pass2 was gated on carry_15 anyway -> no added critical
// path. Early waves write y while late waves read x -> read/write overlap.
// Single tiny init barrier for LDS flag zeroing only.
// Layout unchanged from v3: wave = 64 consecutive d (256B-clean), block =
// 1024 thr = 64d x 16 chunks (CL=32), grid = 32x8 = 256 blocks = 1/CU.

#define SSM_BATCH 8
#define SSM_SEQ 512
#define SSM_D 2048
#define SSM_N 16
#define NC 16
#define CL 32
#define DPB 64

typedef float float4v __attribute__((ext_vector_type(4)));

static __device__ inline float4v fma4(float4v a, float4v b, float4v c) {
    return (float4v){fmaf(a.x, b.x, c.x), fmaf(a.y, b.y, c.y),
                     fmaf(a.z, b.z, c.z), fmaf(a.w, b.w, c.w)};
}
static __device__ inline float4v exp4(float4v v) {
    return (float4v){expf(v.x), expf(v.y), expf(v.z), expf(v.w)};
}

__global__ __launch_bounds__(1024, 4) void ssm_fused4(
    const float* __restrict__ x, const float* __restrict__ A_log,
    const float* __restrict__ Bm, const float* __restrict__ Cm,
    const float* __restrict__ log_dt, float* __restrict__ out)
{
    const int tid = threadIdx.x;
    const int dl  = tid & (DPB - 1);   // lane = channel within block
    const int c   = tid >> 6;          // chunk index 0..15 == wave id
    const int d   = blockIdx.x * DPB + dl;
    const int b   = blockIdx.y;

    __shared__ float4v S4[DPB * 4 * 17];        // U_c / carry_c exchange (69632 B)
    __shared__ unsigned uflag[NC];              // U_c published
    __shared__ unsigned cflag[NC];              // carry_c published

    if (tid < NC) { uflag[tid] = 0u; cflag[tid] = 0u; }
    __syncthreads();   // flag init only — before any memory work

    // ---- issue all 32 x loads up front (scan-independent -> max MLP) ----
    const size_t xoff = ((size_t)b * SSM_SEQ + c * CL) * SSM_D + d;
    const float* xp = x + xoff;
    float xb[CL];
    #pragma unroll
    for (int t = 0; t < CL; ++t) xb[t] = xp[(size_t)t * SSM_D];

    // ---- per-channel params (exp chain overlaps loads) ----
    const float dt = expf(log_dt[d]);
    float4v dA[4];
    #pragma unroll
    for (int j = 0; j < 4; ++j) {
        float4v al = *(const float4v*)(A_log + d * SSM_N + 4 * j);
        dA[j] = exp4(dt * exp4(al));
    }

    // ---- pass 1: chunk-local scan from 0 -> U_c ----
    float4v u[4];
    #pragma unroll
    for (int j = 0; j < 4; ++j) u[j] = (float4v)0.f;
    #pragma unroll
    for (int t = 0; t < CL; ++t) {
        const float xv = xb[t];
        const float4v xs = {xv, xv, xv, xv};
        #pragma unroll
        for (int j = 0; j < 4; ++j) u[j] = fma4(dA[j], u[j], xs);
    }

    const int row = dl * 4;
    if (c < NC - 1) {
        // publish U_c (wave 15 keeps U_15 in registers; nobody consumes it)
        #pragma unroll
        for (int j = 0; j < 4; ++j) S4[(row + j) * 17 + c] = u[j];
        __threadfence_block();
        if (dl == 0) atomicExch(&uflag[c], 1u);
    }

    // ---- dBC (pass-2-only param): issue these loads before any polling ----
    float4v dBC[4];
    #pragma unroll
    for (int j = 0; j < 4; ++j) {
        float4v bv = *(const float4v*)(Bm + d * SSM_N + 4 * j);
        float4v cv = *(const float4v*)(Cm + d * SSM_N + 4 * j);
        dBC[j] = (dt * bv) * cv;
    }

    if (c == NC - 1) {
        // ---- publisher: incremental combine, lane dl owns channel d ----
        float4v dAL[4];
        #pragma unroll
        for (int j = 0; j < 4; ++j) {
            float4v al = *(const float4v*)(A_log + d * SSM_N + 4 * j);
            dAL[j] = exp4(((float)CL * dt) * exp4(al));   // dA^CL
        }
        float4v H[4];
        #pragma unroll
        for (int j = 0; j < 4; ++j) H[j] = (float4v)0.f;

        for (int cc = 0; cc < NC - 1; ++cc) {
            while (atomicAdd(&uflag[cc], 0u) == 0u) __builtin_amdgcn_s_sleep(1);
            __threadfence_block();
            float4v Ucc[4];
            #pragma unroll
            for (int j = 0; j < 4; ++j) Ucc[j] = S4[(row + j) * 17 + cc];
            // carry for chunk cc is the exclusive prefix H (overwrite slot)
            #pragma unroll
            for (int j = 0; j < 4; ++j) S4[(row + j) * 17 + cc] = H[j];
            __threadfence_block();
            if (dl == 0) atomicExch(&cflag[cc], 1u);
            #pragma unroll
            for (int j = 0; j < 4; ++j) H[j] = fma4(dAL[j], H[j], Ucc[j]);
        }
        // H is now the carry for chunk 15 (prefix through U_14)
        #pragma unroll
        for (int j = 0; j < 4; ++j) u[j] = H[j];
    } else if (c == 0) {
        #pragma unroll
        for (int j = 0; j < 4; ++j) u[j] = (float4v)0.f;   // carry_0 = 0, no wait
    } else {
        while (atomicAdd(&cflag[c], 0u) == 0u) __builtin_amdgcn_s_sleep(1);
        __threadfence_block();
        #pragma unroll
        for (int j = 0; j < 4; ++j) u[j] = S4[(row + j) * 17 + c];   // carry-in
    }

    // ---- pass 2: rescan from carry, reuse x still in registers, emit y ----
    float* op = out + xoff;
    #pragma unroll
    for (int t = 0; t < CL; ++t) {
        const float xv = xb[t];
        const float4v xs = {xv, xv, xv, xv};
        #pragma unroll
        for (int j = 0; j < 4; ++j) u[j] = fma4(dA[j], u[j], xs);
        float4v p = dBC[0] * u[0];
        p = fma4(dBC[1], u[1], p);
        p = fma4(dBC[2], u[2], p);
        p = fma4(dBC[3], u[3], p);
        op[(size_t)t * SSM_D] = (p.x + p.y) + (p.z + p.w);
    }
}

extern "C" void kernel_launch(void* const* d_in, const int* in_sizes, int n_in,
                              void* d_out, int out_size, void* d_ws, size_t ws_size,
                              hipStream_t stream) {
    const float* x      = (const float*)d_in[0];
    const float* A_log  = (const float*)d_in[1];
    const float* B      = (const float*)d_in[2];
    const float* C      = (const float*)d_in[3];
    const float* log_dt = (const float*)d_in[4];
    float* out = (float*)d_out;

    dim3 grid(SSM_D / DPB, SSM_BATCH);   // 32 x 8 = 256 blocks, 1 block/CU
    ssm_fused4<<<grid, DPB * NC, 0, stream>>>(x, A_log, B, C, log_dt, out);
}

// Round 7
// 106.528 us; speedup vs baseline: 1.0599x; 1.0599x over previous
//
#include <hip/hip_runtime.h>
#include <math.h>

// SSM diagonal scan v5: LDS-transposed tiles, >=1KB contiguous global segments.
//   reference: h_t = dA ⊙ h_{t-1} + dB·x_t ;  y_t = <C, h_t>
//   dt=exp(log_dt), A=exp(A_log), dA=exp(dt*A), dB=dt*B (time-invariant).
// Algebra: u_n(t)=dA_n·u_n(t-1)+x_t (x unscaled), y_t=Σ_n dBC_n·u_n, dBC=dt·B·C.
// Chunk carries combine in u-space with dA^CL = exp(CL·dt·A).
//
// Round-6 postmortem: flag-pipeline REGRESSED (100.8->112.9) — phase-serialization
// theory dead. Hard evidence v2: 193MB @ 3.5 TB/s; v3: ~67MB @ ~2.5 TB/s — every
// variant uses 256B segments scattered at 8KB stride (lane-per-d, t-major) and
// lands at 40-55% DRAM efficiency, while the harness's sequential fills hit 6 TB/s.
// v5 fixes SEGMENT SIZE: block owns 256d x 64t tile; stage x global->LDS with
// float4/lane = 1KB/wave-instr; scan reads LDS (conflict-free: whole wave reads
// one 256-float row, 2-way alias = free); y overwrites the same LDS cell (same
// thread reads+writes it — race-free, no barrier); cooperative write-out in 1KB
// segments. Carries: NC=8 chunks of CL=64 (numerics validated in round 2);
// kernel1 stores chunk-states U to ws, kernel2 combines its own prefix (<=7
// states, 4KB-contiguous loads, L2/L3-warm) then rescans; x re-read in k2 hits
// the 256MB L3 (67MB working set). Grid 8x8x8=512 blocks = 2/CU (LDS 64KB).

#define SSM_BATCH 8
#define SSM_SEQ 512
#define SSM_D 2048
#define SSM_N 16
#define NCH 8          // chunks per sequence
#define CLEN 64        // chunk length
#define DT 256         // d-channels per block tile

typedef float float4v __attribute__((ext_vector_type(4)));

static __device__ inline float4v fma4(float4v a, float4v b, float4v c) {
    return (float4v){fmaf(a.x, b.x, c.x), fmaf(a.y, b.y, c.y),
                     fmaf(a.z, b.z, c.z), fmaf(a.w, b.w, c.w)};
}
static __device__ inline float4v exp4(float4v v) {
    return (float4v){expf(v.x), expf(v.y), expf(v.z), expf(v.w)};
}

// ---------------- kernel 1: local chunk scan -> U ----------------
__global__ __launch_bounds__(256, 2) void ssm_k1(
    const float* __restrict__ x, const float* __restrict__ A_log,
    const float* __restrict__ log_dt, float* __restrict__ U)
{
    const int tid   = threadIdx.x;
    const int dtile = blockIdx.x, c = blockIdx.y, b = blockIdx.z;
    __shared__ float xs[CLEN * DT];          // 64 KB

    const int trow = tid >> 6;               // 0..3
    const int col4 = (tid & 63) * 4;         // 0..252
    const float* gx = x + ((size_t)(b * SSM_SEQ + c * CLEN)) * SSM_D + dtile * DT;

    // stage-in: 16 iters x 4 rows; each wave-instr = 1KB contiguous
    float4 stg[16];
    #pragma unroll
    for (int r = 0; r < 16; ++r)
        stg[r] = *(const float4*)(gx + (size_t)(r * 4 + trow) * SSM_D + col4);

    const int d = dtile * DT + tid;
    const float dt = expf(log_dt[d]);
    float4v dA[4];
    #pragma unroll
    for (int j = 0; j < 4; ++j) {
        float4v al = *(const float4v*)(A_log + d * SSM_N + 4 * j);
        dA[j] = exp4(dt * exp4(al));
    }

    #pragma unroll
    for (int r = 0; r < 16; ++r)
        *(float4*)(&xs[(r * 4 + trow) * DT + col4]) = stg[r];
    __syncthreads();

    float4v u[4];
    #pragma unroll
    for (int j = 0; j < 4; ++j) u[j] = (float4v)0.f;
    #pragma unroll 8
    for (int t = 0; t < CLEN; ++t) {
        const float xv = xs[t * DT + tid];
        const float4v xsv = {xv, xv, xv, xv};
        #pragma unroll
        for (int j = 0; j < 4; ++j) u[j] = fma4(dA[j], u[j], xsv);
    }

    float* up = U + (((size_t)c * SSM_BATCH + b) * SSM_D + d) * SSM_N;
    #pragma unroll
    for (int j = 0; j < 4; ++j) *(float4v*)(up + 4 * j) = u[j];
}

// ---------------- kernel 2: combine prefix + rescan -> y ----------------
__global__ __launch_bounds__(256, 2) void ssm_k2(
    const float* __restrict__ x, const float* __restrict__ A_log,
    const float* __restrict__ Bm, const float* __restrict__ Cm,
    const float* __restrict__ log_dt, const float* __restrict__ U,
    float* __restrict__ out)
{
    const int tid   = threadIdx.x;
    const int dtile = blockIdx.x, c = blockIdx.y, b = blockIdx.z;
    __shared__ float xs[CLEN * DT];          // 64 KB

    const int trow = tid >> 6;
    const int col4 = (tid & 63) * 4;
    const size_t goff = ((size_t)(b * SSM_SEQ + c * CLEN)) * SSM_D + dtile * DT;
    const float* gx = x + goff;

    float4 stg[16];
    #pragma unroll
    for (int r = 0; r < 16; ++r)
        stg[r] = *(const float4*)(gx + (size_t)(r * 4 + trow) * SSM_D + col4);

    const int d = dtile * DT + tid;
    const float dt = expf(log_dt[d]);
    float4v dA[4], dBC[4];
    #pragma unroll
    for (int j = 0; j < 4; ++j) {
        float4v al = *(const float4v*)(A_log + d * SSM_N + 4 * j);
        float4v bv = *(const float4v*)(Bm + d * SSM_N + 4 * j);
        float4v cv = *(const float4v*)(Cm + d * SSM_N + 4 * j);
        dA[j]  = exp4(dt * exp4(al));
        dBC[j] = (dt * bv) * cv;
    }

    #pragma unroll
    for (int r = 0; r < 16; ++r)
        *(float4*)(&xs[(r * 4 + trow) * DT + col4]) = stg[r];

    // combine own prefix: H = carry-in for chunk c (exclusive scan of U)
    float4v H[4];
    #pragma unroll
    for (int j = 0; j < 4; ++j) H[j] = (float4v)0.f;
    if (c > 0) {
        float4v dAL[4];
        #pragma unroll
        for (int j = 0; j < 4; ++j) {
            float4v al = *(const float4v*)(A_log + d * SSM_N + 4 * j);
            dAL[j] = exp4(((float)CLEN * dt) * exp4(al));   // dA^CL
        }
        for (int cc = 0; cc < c; ++cc) {
            const float* up = U + (((size_t)cc * SSM_BATCH + b) * SSM_D + d) * SSM_N;
            float4v Uc[4];
            #pragma unroll
            for (int j = 0; j < 4; ++j) Uc[j] = *(const float4v*)(up + 4 * j);
            #pragma unroll
            for (int j = 0; j < 4; ++j) H[j] = fma4(dAL[j], H[j], Uc[j]);
        }
    }
    __syncthreads();

    // rescan from carry; overwrite own LDS column with y (race-free in-place)
    #pragma unroll 8
    for (int t = 0; t < CLEN; ++t) {
        const float xv = xs[t * DT + tid];
        const float4v xsv = {xv, xv, xv, xv};
        #pragma unroll
        for (int j = 0; j < 4; ++j) H[j] = fma4(dA[j], H[j], xsv);
        float4v p = dBC[0] * H[0];
        p = fma4(dBC[1], H[1], p);
        p = fma4(dBC[2], H[2], p);
        p = fma4(dBC[3], H[3], p);
        xs[t * DT + tid] = (p.x + p.y) + (p.z + p.w);
    }
    __syncthreads();

    // write-out: 1KB contiguous per wave-instr
    float* gy = out + goff;
    #pragma unroll
    for (int r = 0; r < 16; ++r) {
        float4 v = *(const float4*)(&xs[(r * 4 + trow) * DT + col4]);
        *(float4*)(gy + (size_t)(r * 4 + trow) * SSM_D + col4) = v;
    }
}

extern "C" void kernel_launch(void* const* d_in, const int* in_sizes, int n_in,
                              void* d_out, int out_size, void* d_ws, size_t ws_size,
                              hipStream_t stream) {
    const float* x      = (const float*)d_in[0];
    const float* A_log  = (const float*)d_in[1];
    const float* B      = (const float*)d_in[2];
    const float* C      = (const float*)d_in[3];
    const float* log_dt = (const float*)d_in[4];
    float* out = (float*)d_out;
    float* U   = (float*)d_ws;   // NCH * BATCH * D * N floats = 8 MB

    dim3 grid(SSM_D / DT, NCH, SSM_BATCH);   // 8 x 8 x 8 = 512 blocks, 2/CU
    ssm_k1<<<grid, DT, 0, stream>>>(x, A_log, log_dt, U);
    ssm_k2<<<grid, DT, 0, stream>>>(x, A_log, B, C, log_dt, U, out);
}

// Round 9
// 103.683 us; speedup vs baseline: 1.0889x; 1.0274x over previous
//
#include <hip/hip_runtime.h>
#include <math.h>

// SSM diagonal scan v6b: v6 with the nontemporal-store type fixed (ext-vector,
// not HIP_vector_type — __builtin_nontemporal_store rejects struct types).
//   reference: h_t = dA ⊙ h_{t-1} + dB·x_t ;  y_t = <C, h_t>
//   dt=exp(log_dt), A=exp(A_log), dA=exp(dt*A), dB=dt*B (time-invariant).
// Algebra: u_n(t)=dA_n·u_n(t-1)+x_t, y_t=Σ_n dBC_n·u_n, dBC=dt·B·C.
// Carries: NCH=8 chunks of CLEN=64; U[c] = chunk-local final state; carry for
// chunk c = exclusive prefix with multiplier dA^CLEN (redundant per-block combine).
//
// v5->v6 changes (theory from round 7 postmortem — v5 hit the ~3.5 TB/s mixed
// effective ceiling; problem is BYTES not efficiency):
//  (1) U layout [c][b][n-quad j][d] float4 planes: consecutive-d lanes ->
//      1KB-contiguous wave-instrs, 16MB true each way (v5's 64B-stride float4
//      per-thread stores were ~4x granule-amplified).
//  (2) y written with nontemporal stores (never re-read) -> L2/L3 unpolluted,
//      so K2's x re-read stays an L3 hit (x fetched from HBM once, in K1).
//  (3) K2: x-tile loads issued first; prefix combine runs under their latency.
// Grid 8x8x8 = 512 blocks of 256 thr, 2 blocks/CU (64KB LDS each).

#define SSM_BATCH 8
#define SSM_SEQ 512
#define SSM_D 2048
#define SSM_N 16
#define NCH 8          // chunks per sequence
#define CLEN 64        // chunk length
#define DT 256         // d-channels per block tile

typedef float float4v __attribute__((ext_vector_type(4)));

static __device__ inline float4v fma4(float4v a, float4v b, float4v c) {
    return (float4v){fmaf(a.x, b.x, c.x), fmaf(a.y, b.y, c.y),
                     fmaf(a.z, b.z, c.z), fmaf(a.w, b.w, c.w)};
}
static __device__ inline float4v exp4(float4v v) {
    return (float4v){expf(v.x), expf(v.y), expf(v.z), expf(v.w)};
}

// U plane index: (((c*BATCH + b)*4 + j)*D + d)  as float4 elements (n-quad j)
static __device__ inline size_t uidx(int c, int b, int j, int d) {
    return (((size_t)c * SSM_BATCH + b) * 4 + j) * SSM_D + d;
}

// ---------------- kernel 1: local chunk scan -> U ----------------
__global__ __launch_bounds__(256, 2) void ssm_k1(
    const float* __restrict__ x, const float* __restrict__ A_log,
    const float* __restrict__ log_dt, float4v* __restrict__ U4)
{
    const int tid   = threadIdx.x;
    const int dtile = blockIdx.x, c = blockIdx.y, b = blockIdx.z;
    __shared__ float xs[CLEN * DT];          // 64 KB

    const int trow = tid >> 6;               // 0..3
    const int col4 = (tid & 63) * 4;         // 0..252
    const float* gx = x + ((size_t)(b * SSM_SEQ + c * CLEN)) * SSM_D + dtile * DT;

    // stage-in: each wave-instr = 1KB contiguous
    float4v stg[16];
    #pragma unroll
    for (int r = 0; r < 16; ++r)
        stg[r] = *(const float4v*)(gx + (size_t)(r * 4 + trow) * SSM_D + col4);

    const int d = dtile * DT + tid;
    const float dt = expf(log_dt[d]);
    float4v dA[4];
    #pragma unroll
    for (int j = 0; j < 4; ++j) {
        float4v al = *(const float4v*)(A_log + d * SSM_N + 4 * j);
        dA[j] = exp4(dt * exp4(al));
    }

    #pragma unroll
    for (int r = 0; r < 16; ++r)
        *(float4v*)(&xs[(r * 4 + trow) * DT + col4]) = stg[r];
    __syncthreads();

    float4v u[4];
    #pragma unroll
    for (int j = 0; j < 4; ++j) u[j] = (float4v)0.f;
    #pragma unroll 8
    for (int t = 0; t < CLEN; ++t) {
        const float xv = xs[t * DT + tid];
        const float4v xsv = {xv, xv, xv, xv};
        #pragma unroll
        for (int j = 0; j < 4; ++j) u[j] = fma4(dA[j], u[j], xsv);
    }

    // U store: [c][b][j][d] planes -> consecutive-d lanes contiguous (1KB/instr)
    #pragma unroll
    for (int j = 0; j < 4; ++j) U4[uidx(c, b, j, d)] = u[j];
}

// ---------------- kernel 2: combine prefix + rescan -> y ----------------
__global__ __launch_bounds__(256, 2) void ssm_k2(
    const float* __restrict__ x, const float* __restrict__ A_log,
    const float* __restrict__ Bm, const float* __restrict__ Cm,
    const float* __restrict__ log_dt, const float4v* __restrict__ U4,
    float* __restrict__ out)
{
    const int tid   = threadIdx.x;
    const int dtile = blockIdx.x, c = blockIdx.y, b = blockIdx.z;
    __shared__ float xs[CLEN * DT];          // 64 KB

    const int trow = tid >> 6;
    const int col4 = (tid & 63) * 4;
    const size_t goff = ((size_t)(b * SSM_SEQ + c * CLEN)) * SSM_D + dtile * DT;
    const float* gx = x + goff;

    // x-tile loads first (L3-warm from K1); combine runs under their latency
    float4v stg[16];
    #pragma unroll
    for (int r = 0; r < 16; ++r)
        stg[r] = *(const float4v*)(gx + (size_t)(r * 4 + trow) * SSM_D + col4);

    const int d = dtile * DT + tid;
    const float dt = expf(log_dt[d]);
    float4v dA[4], dBC[4];
    #pragma unroll
    for (int j = 0; j < 4; ++j) {
        float4v al = *(const float4v*)(A_log + d * SSM_N + 4 * j);
        float4v bv = *(const float4v*)(Bm + d * SSM_N + 4 * j);
        float4v cv = *(const float4v*)(Cm + d * SSM_N + 4 * j);
        dA[j]  = exp4(dt * exp4(al));
        dBC[j] = (dt * bv) * cv;
    }

    // combine own prefix: H = carry-in for chunk c (exclusive scan of U)
    float4v H[4];
    #pragma unroll
    for (int j = 0; j < 4; ++j) H[j] = (float4v)0.f;
    if (c > 0) {
        float4v dAL[4];
        #pragma unroll
        for (int j = 0; j < 4; ++j) {
            float4v al = *(const float4v*)(A_log + d * SSM_N + 4 * j);
            dAL[j] = exp4(((float)CLEN * dt) * exp4(al));   // dA^CLEN
        }
        for (int cc = 0; cc < c; ++cc) {
            float4v Uc[4];
            #pragma unroll
            for (int j = 0; j < 4; ++j) Uc[j] = U4[uidx(cc, b, j, d)];
            #pragma unroll
            for (int j = 0; j < 4; ++j) H[j] = fma4(dAL[j], H[j], Uc[j]);
        }
    }

    #pragma unroll
    for (int r = 0; r < 16; ++r)
        *(float4v*)(&xs[(r * 4 + trow) * DT + col4]) = stg[r];
    __syncthreads();

    // rescan from carry; overwrite own LDS column with y (race-free in-place)
    #pragma unroll 8
    for (int t = 0; t < CLEN; ++t) {
        const float xv = xs[t * DT + tid];
        const float4v xsv = {xv, xv, xv, xv};
        #pragma unroll
        for (int j = 0; j < 4; ++j) H[j] = fma4(dA[j], H[j], xsv);
        float4v p = dBC[0] * H[0];
        p = fma4(dBC[1], H[1], p);
        p = fma4(dBC[2], H[2], p);
        p = fma4(dBC[3], H[3], p);
        xs[t * DT + tid] = (p.x + p.y) + (p.z + p.w);
    }
    __syncthreads();

    // write-out: 1KB contiguous per wave-instr, nontemporal (y never re-read)
    float* gy = out + goff;
    #pragma unroll
    for (int r = 0; r < 16; ++r) {
        float4v v = *(const float4v*)(&xs[(r * 4 + trow) * DT + col4]);
        __builtin_nontemporal_store(v, (float4v*)(gy + (size_t)(r * 4 + trow) * SSM_D + col4));
    }
}

extern "C" void kernel_launch(void* const* d_in, const int* in_sizes, int n_in,
                              void* d_out, int out_size, void* d_ws, size_t ws_size,
                              hipStream_t stream) {
    const float* x      = (const float*)d_in[0];
    const float* A_log  = (const float*)d_in[1];
    const float* B      = (const float*)d_in[2];
    const float* C      = (const float*)d_in[3];
    const float* log_dt = (const float*)d_in[4];
    float* out = (float*)d_out;
    float4v* U4 = (float4v*)d_ws;   // NCH*BATCH*4*D float4 = 16 MB

    dim3 grid(SSM_D / DT, NCH, SSM_BATCH);   // 8 x 8 x 8 = 512 blocks, 2/CU
    ssm_k1<<<grid, DT, 0, stream>>>(x, A_log, log_dt, U4);
    ssm_k2<<<grid, DT, 0, stream>>>(x, A_log, B, C, log_dt, U4, out);
}